// Round 1
// baseline (1411.464 us; speedup 1.0000x reference)
//
#include <hip/hip_runtime.h>
#include <math.h>

// Problem constants (B,S,H from reference)
#define Bb 4
#define Ss 2048
#define Hh 1024
#define Ff 513          // H/2 + 1 rfft bins
#define FEAT 1026       // cos||sin feature length
#define KP 1040         // padded K stride (65 * 16)

// ---------------------------------------------------------------------------
// Kernel 1: per-row 1024-pt FFT -> unit-phase features [cos(0..512), sin(0..512)]
// grid: (B*S, 2) ; blockIdx.y: 0 = Q, 1 = K. 256 threads.
// cos(phase) = re/|z|, sin(phase) = im/|z|  (atan2 never needed)
// ---------------------------------------------------------------------------
__global__ __launch_bounds__(256) void fft_phase_kernel(
    const float* __restrict__ Q, const float* __restrict__ K,
    float* __restrict__ FQ, float* __restrict__ FK) {
  const int row = blockIdx.x;
  const float* src = (blockIdx.y == 0 ? Q : K) + (size_t)row * Hh;
  float* dst = (blockIdx.y == 0 ? FQ : FK) + (size_t)row * KP;

  __shared__ float2 data[1024];
  const int tid = threadIdx.x;

  // load with 10-bit bit-reversal (DIT), imag = 0
#pragma unroll
  for (int e = 0; e < 4; ++e) {
    const int i = tid + e * 256;
    const int r = (int)(__brev((unsigned)i) >> 22);
    data[r] = make_float2(src[i], 0.0f);
  }
  __syncthreads();

  // radix-2 DIT stages; 512 butterflies/stage, 2 per thread.
  // Butterfly pairs partition the array -> no intra-stage hazards.
  for (int len = 2; len <= 1024; len <<= 1) {
    const int half = len >> 1;
    const float ang = -6.283185307179586f / (float)len;
#pragma unroll
    for (int e = 0; e < 2; ++e) {
      const int t = tid + e * 256;        // 0..511
      const int j = t & (half - 1);
      const int pos = 2 * t - j;          // group*len + j
      float sw, cw;
      sincosf(ang * (float)j, &sw, &cw);
      const float2 u = data[pos];
      const float2 v = data[pos + half];
      const float vr = v.x * cw - v.y * sw;
      const float vi = v.x * sw + v.y * cw;
      data[pos]        = make_float2(u.x + vr, u.y + vi);
      data[pos + half] = make_float2(u.x - vr, u.y - vi);
    }
    __syncthreads();
  }

  // normalize bins 0..512 to unit circle; write cos then sin; zero the pad
  for (int f = tid; f < Ff; f += 256) {
    const float2 z = data[f];
    const float mag = sqrtf(z.x * z.x + z.y * z.y);
    float c, s;
    if (mag > 0.0f) { c = z.x / mag; s = z.y / mag; }
    else            { c = 1.0f;      s = 0.0f; }
    dst[f] = c;
    dst[Ff + f] = s;
  }
  for (int p = FEAT + tid; p < KP; p += 256) dst[p] = 0.0f;
}

// ---------------------------------------------------------------------------
// Kernel 2: scores[b,i,j] = dot(Fq[b,i,:], Fk[b,j,:]) / 513 + 1
// fp32 LDS-tiled GEMM, 64x64 tile, BK=16, 256 threads, 4x4 per thread.
// grid: (S/64, S/64, B)
// ---------------------------------------------------------------------------
__global__ __launch_bounds__(256) void score_gemm_kernel(
    const float* __restrict__ FQ, const float* __restrict__ FK,
    float* __restrict__ Wout) {
  const int b  = blockIdx.z;
  const int i0 = blockIdx.y * 64;
  const int j0 = blockIdx.x * 64;
  const float* Arow = FQ + (size_t)b * Ss * KP;
  const float* Brow = FK + (size_t)b * Ss * KP;
  float* W = Wout + (size_t)b * Ss * Ss;

  __shared__ float As[16][65];
  __shared__ float Bs[16][65];

  const int tid  = threadIdx.x;
  const int tx   = tid & 15;
  const int ty   = tid >> 4;
  const int lrow = tid >> 2;          // 0..63
  const int lk   = (tid & 3) * 4;     // 0,4,8,12

  float acc[4][4] = {};

  for (int k0 = 0; k0 < KP; k0 += 16) {   // 65 iterations (pad contributes 0)
    const float4 a4 = *(const float4*)(Arow + (size_t)(i0 + lrow) * KP + k0 + lk);
    const float4 b4 = *(const float4*)(Brow + (size_t)(j0 + lrow) * KP + k0 + lk);
    __syncthreads();
    As[lk + 0][lrow] = a4.x; As[lk + 1][lrow] = a4.y;
    As[lk + 2][lrow] = a4.z; As[lk + 3][lrow] = a4.w;
    Bs[lk + 0][lrow] = b4.x; Bs[lk + 1][lrow] = b4.y;
    Bs[lk + 2][lrow] = b4.z; Bs[lk + 3][lrow] = b4.w;
    __syncthreads();
#pragma unroll
    for (int kk = 0; kk < 16; ++kk) {
      float a[4], bb[4];
#pragma unroll
      for (int m = 0; m < 4; ++m) a[m]  = As[kk][ty * 4 + m];
#pragma unroll
      for (int n = 0; n < 4; ++n) bb[n] = Bs[kk][tx * 4 + n];
#pragma unroll
      for (int m = 0; m < 4; ++m)
#pragma unroll
        for (int n = 0; n < 4; ++n)
          acc[m][n] = fmaf(a[m], bb[n], acc[m][n]);
    }
  }

  const float inv_f = 1.0f / 513.0f;
#pragma unroll
  for (int m = 0; m < 4; ++m) {
    const int i = i0 + ty * 4 + m;
#pragma unroll
    for (int n = 0; n < 4; ++n) {
      const int j = j0 + tx * 4 + n;
      W[(size_t)i * Ss + j] = acc[m][n] * inv_f + 1.0f;
    }
  }
}

// ---------------------------------------------------------------------------
// Kernel 3: in-place row softmax over 2048 cols. One block (256 thr) per row.
// ---------------------------------------------------------------------------
__global__ __launch_bounds__(256) void softmax_kernel(float* __restrict__ W) {
  const size_t row = blockIdx.x;
  float* p = W + row * (size_t)Ss;
  const int tid = threadIdx.x;
  __shared__ float red[4];

  float v[8];
  float m = -3.0e38f;
#pragma unroll
  for (int e = 0; e < 8; ++e) { v[e] = p[tid + e * 256]; m = fmaxf(m, v[e]); }
#pragma unroll
  for (int off = 32; off > 0; off >>= 1) m = fmaxf(m, __shfl_down(m, off, 64));
  if ((tid & 63) == 0) red[tid >> 6] = m;
  __syncthreads();
  m = fmaxf(fmaxf(red[0], red[1]), fmaxf(red[2], red[3]));

  float sum = 0.0f;
#pragma unroll
  for (int e = 0; e < 8; ++e) { v[e] = expf(v[e] - m); sum += v[e]; }
#pragma unroll
  for (int off = 32; off > 0; off >>= 1) sum += __shfl_down(sum, off, 64);
  __syncthreads();
  if ((tid & 63) == 0) red[tid >> 6] = sum;
  __syncthreads();
  sum = red[0] + red[1] + red[2] + red[3];

  const float rs = 1.0f / sum;
#pragma unroll
  for (int e = 0; e < 8; ++e) p[tid + e * 256] = v[e] * rs;
}

// ---------------------------------------------------------------------------
// Kernel 4: out[b,i,h] = sum_j W[b,i,j] * V[b,j,h]
// fp32 LDS-tiled GEMM, 64x64 tile, BK=16. grid: (H/64, S/64, B)
// ---------------------------------------------------------------------------
__global__ __launch_bounds__(256) void pv_gemm_kernel(
    const float* __restrict__ W, const float* __restrict__ V,
    float* __restrict__ Out) {
  const int b  = blockIdx.z;
  const int i0 = blockIdx.y * 64;
  const int h0 = blockIdx.x * 64;
  const float* A  = W + (size_t)b * Ss * Ss;
  const float* Bv = V + (size_t)b * Ss * Hh;
  float* O = Out + (size_t)b * Ss * Hh;

  __shared__ float As[16][65];
  __shared__ float Bs[16][65];

  const int tid  = threadIdx.x;
  const int tx   = tid & 15;
  const int ty   = tid >> 4;
  const int lrow = tid >> 2;          // A: 0..63 row in tile
  const int lk   = (tid & 3) * 4;     // A: k offset
  const int jj   = tid >> 4;          // B: 0..15 k-row
  const int hh   = (tid & 15) * 4;    // B: col offset

  float acc[4][4] = {};

  for (int k0 = 0; k0 < Ss; k0 += 16) {   // 128 iterations
    const float4 a4 = *(const float4*)(A  + (size_t)(i0 + lrow) * Ss + k0 + lk);
    const float4 b4 = *(const float4*)(Bv + (size_t)(k0 + jj) * Hh + h0 + hh);
    __syncthreads();
    As[lk + 0][lrow] = a4.x; As[lk + 1][lrow] = a4.y;
    As[lk + 2][lrow] = a4.z; As[lk + 3][lrow] = a4.w;
    Bs[jj][hh + 0] = b4.x; Bs[jj][hh + 1] = b4.y;
    Bs[jj][hh + 2] = b4.z; Bs[jj][hh + 3] = b4.w;
    __syncthreads();
#pragma unroll
    for (int kk = 0; kk < 16; ++kk) {
      float a[4], bb[4];
#pragma unroll
      for (int m = 0; m < 4; ++m) a[m]  = As[kk][ty * 4 + m];
#pragma unroll
      for (int n = 0; n < 4; ++n) bb[n] = Bs[kk][tx * 4 + n];
#pragma unroll
      for (int m = 0; m < 4; ++m)
#pragma unroll
        for (int n = 0; n < 4; ++n)
          acc[m][n] = fmaf(a[m], bb[n], acc[m][n]);
    }
  }

#pragma unroll
  for (int m = 0; m < 4; ++m) {
    const int i = i0 + ty * 4 + m;
#pragma unroll
    for (int n = 0; n < 4; ++n) {
      const int h = h0 + tx * 4 + n;
      O[(size_t)i * Hh + h] = acc[m][n];
    }
  }
}

// ---------------------------------------------------------------------------
extern "C" void kernel_launch(void* const* d_in, const int* in_sizes, int n_in,
                              void* d_out, int out_size, void* d_ws, size_t ws_size,
                              hipStream_t stream) {
  const float* Q = (const float*)d_in[0];
  const float* K = (const float*)d_in[1];
  const float* V = (const float*)d_in[2];

  float* out     = (float*)d_out;                      // [B,S,H]
  float* weights = out + (size_t)Bb * Ss * Hh;         // [B,S,S]

  float* FQ = (float*)d_ws;                            // [B,S,KP]
  float* FK = FQ + (size_t)Bb * Ss * KP;               // [B,S,KP]

  hipLaunchKernelGGL(fft_phase_kernel, dim3(Bb * Ss, 2), dim3(256), 0, stream,
                     Q, K, FQ, FK);
  hipLaunchKernelGGL(score_gemm_kernel, dim3(Ss / 64, Ss / 64, Bb), dim3(256), 0, stream,
                     FQ, FK, weights);
  hipLaunchKernelGGL(softmax_kernel, dim3(Bb * Ss), dim3(256), 0, stream,
                     weights);
  hipLaunchKernelGGL(pv_gemm_kernel, dim3(Hh / 64, Ss / 64, Bb), dim3(256), 0, stream,
                     weights, V, out);
}

// Round 2
// 268.930 us; speedup vs baseline: 5.2484x; 5.2484x over previous
//
#include <hip/hip_runtime.h>
#include <hip/hip_bf16.h>
#include <math.h>

// Problem constants
#define Bb 4
#define Ss 2048
#define Hh 1024
#define Ff 513           // H/2 + 1 rfft bins
#define FEAT 1026        // cos||sin feature length
#define KP2 1056         // padded feature K (33 * 32)

typedef __attribute__((ext_vector_type(8))) short bf16x8;
typedef __attribute__((ext_vector_type(4))) float f32x4;

typedef const __attribute__((address_space(1))) void GVoid;
typedef __attribute__((address_space(3))) void LVoid;

// ---------------------------------------------------------------------------
// Kernel 1: per-row 1024-pt FFT -> unit-phase features as bf16
// [cos(0..512), sin(0..512), pad zeros to 1056]. grid (B*S, 2): y=0 Q, y=1 K.
// cos(phase)=re/|z|, sin(phase)=im/|z| (no atan2). Twiddles from LDS table.
// ---------------------------------------------------------------------------
__global__ __launch_bounds__(256) void fft_phase_kernel(
    const float* __restrict__ Q, const float* __restrict__ Kin,
    __hip_bfloat16* __restrict__ FQ, __hip_bfloat16* __restrict__ FK) {
  const int row = blockIdx.x;
  const float* src = (blockIdx.y == 0 ? Q : Kin) + (size_t)row * Hh;
  __hip_bfloat16* dst = (blockIdx.y == 0 ? FQ : FK) + (size_t)row * KP2;

  __shared__ float2 data[1024];
  __shared__ float2 tw[512];
  const int tid = threadIdx.x;

  // twiddle table: tw[m] = exp(-2*pi*i*m/1024)
#pragma unroll
  for (int e = 0; e < 2; ++e) {
    const int m = tid + e * 256;
    float s, c;
    sincosf(-6.283185307179586f * (float)m * (1.0f / 1024.0f), &s, &c);
    tw[m] = make_float2(c, s);
  }
  // bit-reversed load (DIT), imag = 0
#pragma unroll
  for (int e = 0; e < 4; ++e) {
    const int i = tid + e * 256;
    const int r = (int)(__brev((unsigned)i) >> 22);
    data[r] = make_float2(src[i], 0.0f);
  }
  __syncthreads();

  for (int s = 1; s <= 10; ++s) {
    const int half = 1 << (s - 1);
    const int shift = 10 - s;
#pragma unroll
    for (int e = 0; e < 2; ++e) {
      const int t = tid + e * 256;       // 0..511 butterflies
      const int j = t & (half - 1);
      const int pos = 2 * t - j;
      const float2 wv = tw[j << shift];
      const float2 u = data[pos];
      const float2 v = data[pos + half];
      const float vr = v.x * wv.x - v.y * wv.y;
      const float vi = v.x * wv.y + v.y * wv.x;
      data[pos] = make_float2(u.x + vr, u.y + vi);
      data[pos + half] = make_float2(u.x - vr, u.y - vi);
    }
    __syncthreads();
  }

  for (int f = tid; f < Ff; f += 256) {
    const float2 z = data[f];
    const float m2 = z.x * z.x + z.y * z.y;
    float c, s;
    if (m2 > 1e-30f) {
      const float inv = rsqrtf(m2);
      c = z.x * inv; s = z.y * inv;
    } else { c = 1.0f; s = 0.0f; }
    dst[f]      = __float2bfloat16(c);
    dst[Ff + f] = __float2bfloat16(s);
  }
  for (int p = FEAT + tid; p < KP2; p += 256)
    dst[p] = __float2bfloat16(0.0f);
}

// ---------------------------------------------------------------------------
// Kernel 2: V [B,S,H] fp32 -> Vt [B,H,S] bf16 (transpose, LDS 32x33 tile)
// ---------------------------------------------------------------------------
__global__ __launch_bounds__(256) void vt_kernel(
    const float* __restrict__ V, __hip_bfloat16* __restrict__ Vt) {
  const int b = blockIdx.z;
  const int h0 = blockIdx.x * 32;
  const int s0 = blockIdx.y * 32;
  __shared__ float t[32][33];
  const int tid = threadIdx.x;
  const int c = tid & 31;
  const int r8 = tid >> 5;
  const float* Vb = V + (size_t)b * Ss * Hh;
#pragma unroll
  for (int e = 0; e < 4; ++e) {
    const int r = r8 + e * 8;
    t[r][c] = Vb[(size_t)(s0 + r) * Hh + h0 + c];
  }
  __syncthreads();
  __hip_bfloat16* O = Vt + (size_t)b * Hh * Ss;
#pragma unroll
  for (int e = 0; e < 4; ++e) {
    const int hh = r8 + e * 8;
    O[(size_t)(h0 + hh) * Ss + s0 + c] = __float2bfloat16(t[c][hh]);
  }
}

// ---------------------------------------------------------------------------
// bf16 MFMA GEMM, C = A * B^T (both A and B row-major [*, K] bf16).
// 128x128 tile, BK=32, 4 waves, global_load_lds width-16, subtiled LDS layout
// (16-row x 4-kchunk groups) so linear lane-order writes == fragment reads
// -> conflict-free ds_read_b128, no swizzle needed.
// EPI 0: C = acc/513 + 1 (scores).  EPI 1: C = acc (PV output).
// ---------------------------------------------------------------------------
template<int K, int LDA, int LDB, int LDC, int EPI>
__global__ __launch_bounds__(256) void gemm_bt(
    const __hip_bfloat16* __restrict__ Ag, const __hip_bfloat16* __restrict__ Bg,
    float* __restrict__ Cg, size_t strA, size_t strB, size_t strC) {
  const int b = blockIdx.z;
  const int i0 = blockIdx.y * 128;
  const int j0 = blockIdx.x * 128;
  const char* Ab = (const char*)(Ag + (size_t)b * strA);
  const char* Bp = (const char*)(Bg + (size_t)b * strB);
  float* C = Cg + (size_t)b * strC;

  __shared__ short As[4096];   // 8 subtiles x (4 kchunk x 16 row x 8 bf16)
  __shared__ short Bs[4096];

  const int tid = threadIdx.x;
  const int lane = tid & 63;
  const int w = tid >> 6;          // wave 0..3
  const int wm = w >> 1, wn = w & 1;
  const int lrow = lane & 15;
  const int lchunk = lane >> 4;

  f32x4 acc[4][4];
#pragma unroll
  for (int m = 0; m < 4; ++m)
#pragma unroll
    for (int n = 0; n < 4; ++n)
      acc[m][n] = (f32x4){0.0f, 0.0f, 0.0f, 0.0f};

  // per-lane global byte offsets (k part added in loop)
  const size_t aoff0 = (size_t)(i0 + (w    ) * 16 + lrow) * (LDA * 2) + lchunk * 16;
  const size_t aoff1 = (size_t)(i0 + (w + 4) * 16 + lrow) * (LDA * 2) + lchunk * 16;
  const size_t boff0 = (size_t)(j0 + (w    ) * 16 + lrow) * (LDB * 2) + lchunk * 16;
  const size_t boff1 = (size_t)(j0 + (w + 4) * 16 + lrow) * (LDB * 2) + lchunk * 16;

  for (int k0 = 0; k0 < K; k0 += 32) {
    __syncthreads();   // prior compute's ds_reads done before overwrite
    const size_t kb = (size_t)k0 * 2;
    __builtin_amdgcn_global_load_lds((GVoid*)(Ab + aoff0 + kb), (LVoid*)&As[(w    ) * 512], 16, 0, 0);
    __builtin_amdgcn_global_load_lds((GVoid*)(Ab + aoff1 + kb), (LVoid*)&As[(w + 4) * 512], 16, 0, 0);
    __builtin_amdgcn_global_load_lds((GVoid*)(Bp + boff0 + kb), (LVoid*)&Bs[(w    ) * 512], 16, 0, 0);
    __builtin_amdgcn_global_load_lds((GVoid*)(Bp + boff1 + kb), (LVoid*)&Bs[(w + 4) * 512], 16, 0, 0);
    __syncthreads();   // drains vmcnt -> LDS tile ready

    bf16x8 af[4], bfr[4];
#pragma unroll
    for (int m = 0; m < 4; ++m)
      af[m] = *(const bf16x8*)&As[(wm * 4 + m) * 512 + lchunk * 128 + lrow * 8];
#pragma unroll
    for (int n = 0; n < 4; ++n)
      bfr[n] = *(const bf16x8*)&Bs[(wn * 4 + n) * 512 + lchunk * 128 + lrow * 8];
#pragma unroll
    for (int m = 0; m < 4; ++m)
#pragma unroll
      for (int n = 0; n < 4; ++n)
        acc[m][n] = __builtin_amdgcn_mfma_f32_16x16x32_bf16(af[m], bfr[n], acc[m][n], 0, 0, 0);
  }

  // epilogue: C/D layout col = lane&15, row = (lane>>4)*4 + reg  [m89]
  const int r4 = (lane >> 4) * 4;
  const int cc = lane & 15;
#pragma unroll
  for (int m = 0; m < 4; ++m) {
    const int ib = i0 + wm * 64 + m * 16 + r4;
#pragma unroll
    for (int n = 0; n < 4; ++n) {
      const int j = j0 + wn * 64 + n * 16 + cc;
#pragma unroll
      for (int r = 0; r < 4; ++r) {
        float v = acc[m][n][r];
        if (EPI == 0) v = v * (1.0f / 513.0f) + 1.0f;
        C[(size_t)(ib + r) * LDC + j] = v;
      }
    }
  }
}

// ---------------------------------------------------------------------------
// Kernel 3: in-place row softmax over 2048 cols + bf16 copy for PV GEMM.
// ---------------------------------------------------------------------------
__global__ __launch_bounds__(256) void softmax_kernel(
    float* __restrict__ W, __hip_bfloat16* __restrict__ Wb) {
  const size_t row = blockIdx.x;
  float* p = W + row * (size_t)Ss;
  __hip_bfloat16* pb = Wb + row * (size_t)Ss;
  const int tid = threadIdx.x;
  __shared__ float red[4];

  float v[8];
  float m = -3.0e38f;
#pragma unroll
  for (int e = 0; e < 8; ++e) { v[e] = p[tid + e * 256]; m = fmaxf(m, v[e]); }
#pragma unroll
  for (int off = 32; off > 0; off >>= 1) m = fmaxf(m, __shfl_down(m, off, 64));
  if ((tid & 63) == 0) red[tid >> 6] = m;
  __syncthreads();
  m = fmaxf(fmaxf(red[0], red[1]), fmaxf(red[2], red[3]));

  float sum = 0.0f;
#pragma unroll
  for (int e = 0; e < 8; ++e) { v[e] = expf(v[e] - m); sum += v[e]; }
#pragma unroll
  for (int off = 32; off > 0; off >>= 1) sum += __shfl_down(sum, off, 64);
  __syncthreads();
  if ((tid & 63) == 0) red[tid >> 6] = sum;
  __syncthreads();
  sum = red[0] + red[1] + red[2] + red[3];

  const float rs = 1.0f / sum;
#pragma unroll
  for (int e = 0; e < 8; ++e) {
    const float o = v[e] * rs;
    p[tid + e * 256] = o;
    pb[tid + e * 256] = __float2bfloat16(o);
  }
}

// ---------------------------------------------------------------------------
extern "C" void kernel_launch(void* const* d_in, const int* in_sizes, int n_in,
                              void* d_out, int out_size, void* d_ws, size_t ws_size,
                              hipStream_t stream) {
  const float* Q = (const float*)d_in[0];
  const float* K = (const float*)d_in[1];
  const float* V = (const float*)d_in[2];

  float* out     = (float*)d_out;                       // [B,S,H]
  float* weights = out + (size_t)Bb * Ss * Hh;          // [B,S,S]

  // workspace layout:
  //   FQb [B,S,KP2] bf16 | FKb [B,S,KP2] bf16 | Vtb [B,H,S] bf16
  //   Wb  [B,S,S]   bf16 aliases the FQb/FKb region (dead after score GEMM)
  __hip_bfloat16* FQb = (__hip_bfloat16*)d_ws;
  __hip_bfloat16* FKb = FQb + (size_t)Bb * Ss * KP2;
  __hip_bfloat16* Vtb = FKb + (size_t)Bb * Ss * KP2;
  __hip_bfloat16* Wb  = (__hip_bfloat16*)d_ws;

  hipLaunchKernelGGL(fft_phase_kernel, dim3(Bb * Ss, 2), dim3(256), 0, stream,
                     Q, K, FQb, FKb);
  hipLaunchKernelGGL(vt_kernel, dim3(Hh / 32, Ss / 32, Bb), dim3(256), 0, stream,
                     V, Vtb);
  hipLaunchKernelGGL((gemm_bt<KP2, KP2, KP2, Ss, 0>), dim3(16, 16, Bb), dim3(256), 0, stream,
                     FQb, FKb, weights,
                     (size_t)Ss * KP2, (size_t)Ss * KP2, (size_t)Ss * Ss);
  hipLaunchKernelGGL(softmax_kernel, dim3(Bb * Ss), dim3(256), 0, stream,
                     weights, Wb);
  hipLaunchKernelGGL((gemm_bt<Ss, Ss, Ss, Hh, 1>), dim3(8, 16, Bb), dim3(256), 0, stream,
                     Wb, Vtb, out,
                     (size_t)Ss * Ss, (size_t)Hh * Ss, (size_t)Ss * Hh);
}

// Round 3
// 204.139 us; speedup vs baseline: 6.9142x; 1.3174x over previous
//
#include <hip/hip_runtime.h>
#include <hip/hip_bf16.h>
#include <math.h>

// Problem constants
#define Bb 4
#define Ss 2048
#define Hh 1024
#define Ff 513           // H/2 + 1 rfft bins
#define FEAT 1026        // cos||sin feature length
#define KP2 1056         // padded feature K (33 * 32)

typedef __attribute__((ext_vector_type(8))) short bf16x8;
typedef __attribute__((ext_vector_type(4))) float f32x4;

typedef const __attribute__((address_space(1))) void GVoid;
typedef __attribute__((address_space(3))) void LVoid;

// padded LDS index for float2 arrays: breaks power-of-2 stride conflicts
#define PADI(i) ((i) + ((i) >> 4))

__device__ __forceinline__ float2 cmul(float2 a, float2 b) {
  return make_float2(a.x * b.x - a.y * b.y, a.x * b.y + a.y * b.x);
}

// ---------------------------------------------------------------------------
// Kernel 1: packed-real FFT. One block per (b,s) row-pair: z = Q_row + i*K_row,
// single 1024-pt radix-4 DIT FFT (5 stages, 1 butterfly/thread/stage), then
// untangle  Qfft[k] ~ Z[k]+conj(Z[N-k]),  Kfft[k] ~ -i*(Z[k]-conj(Z[N-k]))
// (the /2 cancels in unit-normalization). Emit bf16 [cos||sin] features.
// ---------------------------------------------------------------------------
__global__ __launch_bounds__(256) void fft_phase_kernel(
    const float* __restrict__ Q, const float* __restrict__ Kin,
    __hip_bfloat16* __restrict__ FQ, __hip_bfloat16* __restrict__ FK) {
  const int row = blockIdx.x;                     // 0 .. B*S-1
  const float* qs = Q   + (size_t)row * Hh;
  const float* ks = Kin + (size_t)row * Hh;
  __hip_bfloat16* fq = FQ + (size_t)row * KP2;
  __hip_bfloat16* fk = FK + (size_t)row * KP2;

  __shared__ float2 data[PADI(1023) + 1];         // 1087 float2
  __shared__ float2 tw[1024];                     // W_N^m = exp(-2*pi*i*m/N)
  const int tid = threadIdx.x;

#pragma unroll
  for (int e = 0; e < 4; ++e) {
    const int m = tid + e * 256;
    float s, c;
    sincosf(-6.283185307179586f * (float)m * (1.0f / 1024.0f), &s, &c);
    tw[m] = make_float2(c, s);
  }
  // packed load at base-4 digit-reversed positions (DIT)
#pragma unroll
  for (int e = 0; e < 4; ++e) {
    const int n = tid + e * 256;
    const int r4 = ((n & 3) << 8) | (((n >> 2) & 3) << 6) | (((n >> 4) & 3) << 4)
                 | (((n >> 6) & 3) << 2) | ((n >> 8) & 3);
    data[PADI(r4)] = make_float2(qs[n], ks[n]);
  }
  __syncthreads();

  // 5 radix-4 stages; butterflies partition the array -> 1 sync per stage
  int quarter = 1, step = 256;                    // step = N/len
  for (int s = 0; s < 5; ++s) {
    const int j = tid & (quarter - 1);
    const int pos = 4 * tid - 3 * j;
    const float2 x0 = data[PADI(pos)];
    const float2 x1 = data[PADI(pos + quarter)];
    const float2 x2 = data[PADI(pos + 2 * quarter)];
    const float2 x3 = data[PADI(pos + 3 * quarter)];
    const int e1 = j * step;
    const float2 a1 = cmul(x1, tw[e1]);
    const float2 a2 = cmul(x2, tw[2 * e1]);
    const float2 a3 = cmul(x3, tw[3 * e1]);
    const float2 t0 = make_float2(x0.x + a2.x, x0.y + a2.y);
    const float2 t1 = make_float2(x0.x - a2.x, x0.y - a2.y);
    const float2 t2 = make_float2(a1.x + a3.x, a1.y + a3.y);
    const float2 t3 = make_float2(a1.x - a3.x, a1.y - a3.y);
    data[PADI(pos)]               = make_float2(t0.x + t2.x, t0.y + t2.y);
    data[PADI(pos + quarter)]     = make_float2(t1.x + t3.y, t1.y - t3.x); // t1 - i*t3
    data[PADI(pos + 2 * quarter)] = make_float2(t0.x - t2.x, t0.y - t2.y);
    data[PADI(pos + 3 * quarter)] = make_float2(t1.x - t3.y, t1.y + t3.x); // t1 + i*t3
    __syncthreads();
    quarter <<= 2; step >>= 2;
  }

  // untangle + unit-normalize + bf16 store
  for (int f = tid; f <= 512; f += 256) {
    const float2 z1 = data[PADI(f)];
    const float2 z2 = data[PADI((1024 - f) & 1023)];
    const float qr = z1.x + z2.x, qi = z1.y - z2.y;      // ~ 2*Qfft
    const float kr = z1.y + z2.y, ki = z2.x - z1.x;      // ~ 2*Kfft
    float qc, qsn, kc, ksn;
    const float qm2 = qr * qr + qi * qi;
    if (qm2 > 1e-30f) { const float iv = rsqrtf(qm2); qc = qr * iv; qsn = qi * iv; }
    else              { qc = 1.0f; qsn = 0.0f; }
    const float km2 = kr * kr + ki * ki;
    if (km2 > 1e-30f) { const float iv = rsqrtf(km2); kc = kr * iv; ksn = ki * iv; }
    else              { kc = 1.0f; ksn = 0.0f; }
    fq[f] = __float2bfloat16(qc); fq[Ff + f] = __float2bfloat16(qsn);
    fk[f] = __float2bfloat16(kc); fk[Ff + f] = __float2bfloat16(ksn);
  }
  for (int p = FEAT + tid; p < KP2; p += 256) {
    fq[p] = __float2bfloat16(0.0f);
    fk[p] = __float2bfloat16(0.0f);
  }
}

// ---------------------------------------------------------------------------
// Kernel 2: V [B,S,H] fp32 -> Vt [B,H,S] bf16 (transpose, LDS 32x33 tile)
// ---------------------------------------------------------------------------
__global__ __launch_bounds__(256) void vt_kernel(
    const float* __restrict__ V, __hip_bfloat16* __restrict__ Vt) {
  const int b = blockIdx.z;
  const int h0 = blockIdx.x * 32;
  const int s0 = blockIdx.y * 32;
  __shared__ float t[32][33];
  const int tid = threadIdx.x;
  const int c = tid & 31;
  const int r8 = tid >> 5;
  const float* Vb = V + (size_t)b * Ss * Hh;
#pragma unroll
  for (int e = 0; e < 4; ++e) {
    const int r = r8 + e * 8;
    t[r][c] = Vb[(size_t)(s0 + r) * Hh + h0 + c];
  }
  __syncthreads();
  __hip_bfloat16* O = Vt + (size_t)b * Hh * Ss;
#pragma unroll
  for (int e = 0; e < 4; ++e) {
    const int hh = r8 + e * 8;
    O[(size_t)(h0 + hh) * Ss + s0 + c] = __float2bfloat16(t[c][hh]);
  }
}

// ---------------------------------------------------------------------------
// bf16 MFMA GEMM, C = A * B^T (both row-major [*, K] bf16).
// 128x128 tile, BK=32, 4 waves, global_load_lds width-16, subtiled LDS layout
// -> conflict-free ds_read_b128.  EPI 0: C = acc/513 (scores; +1 dropped —
// softmax is shift-invariant).  EPI 1: C = acc (PV output).
// ---------------------------------------------------------------------------
template<int K, int LDA, int LDB, int LDC, int EPI>
__global__ __launch_bounds__(256) void gemm_bt(
    const __hip_bfloat16* __restrict__ Ag, const __hip_bfloat16* __restrict__ Bg,
    float* __restrict__ Cg, size_t strA, size_t strB, size_t strC) {
  const int b = blockIdx.z;
  const int i0 = blockIdx.y * 128;
  const int j0 = blockIdx.x * 128;
  const char* Ab = (const char*)(Ag + (size_t)b * strA);
  const char* Bp = (const char*)(Bg + (size_t)b * strB);
  float* C = Cg + (size_t)b * strC;

  __shared__ short As[4096];   // 8 subtiles x (4 kchunk x 16 row x 8 bf16)
  __shared__ short Bs[4096];

  const int tid = threadIdx.x;
  const int lane = tid & 63;
  const int w = tid >> 6;
  const int wm = w >> 1, wn = w & 1;
  const int lrow = lane & 15;
  const int lchunk = lane >> 4;

  f32x4 acc[4][4];
#pragma unroll
  for (int m = 0; m < 4; ++m)
#pragma unroll
    for (int n = 0; n < 4; ++n)
      acc[m][n] = (f32x4){0.0f, 0.0f, 0.0f, 0.0f};

  const size_t aoff0 = (size_t)(i0 + (w    ) * 16 + lrow) * (LDA * 2) + lchunk * 16;
  const size_t aoff1 = (size_t)(i0 + (w + 4) * 16 + lrow) * (LDA * 2) + lchunk * 16;
  const size_t boff0 = (size_t)(j0 + (w    ) * 16 + lrow) * (LDB * 2) + lchunk * 16;
  const size_t boff1 = (size_t)(j0 + (w + 4) * 16 + lrow) * (LDB * 2) + lchunk * 16;

  for (int k0 = 0; k0 < K; k0 += 32) {
    __syncthreads();
    const size_t kb = (size_t)k0 * 2;
    __builtin_amdgcn_global_load_lds((GVoid*)(Ab + aoff0 + kb), (LVoid*)&As[(w    ) * 512], 16, 0, 0);
    __builtin_amdgcn_global_load_lds((GVoid*)(Ab + aoff1 + kb), (LVoid*)&As[(w + 4) * 512], 16, 0, 0);
    __builtin_amdgcn_global_load_lds((GVoid*)(Bp + boff0 + kb), (LVoid*)&Bs[(w    ) * 512], 16, 0, 0);
    __builtin_amdgcn_global_load_lds((GVoid*)(Bp + boff1 + kb), (LVoid*)&Bs[(w + 4) * 512], 16, 0, 0);
    __syncthreads();

    bf16x8 af[4], bfr[4];
#pragma unroll
    for (int m = 0; m < 4; ++m)
      af[m] = *(const bf16x8*)&As[(wm * 4 + m) * 512 + lchunk * 128 + lrow * 8];
#pragma unroll
    for (int n = 0; n < 4; ++n)
      bfr[n] = *(const bf16x8*)&Bs[(wn * 4 + n) * 512 + lchunk * 128 + lrow * 8];
#pragma unroll
    for (int m = 0; m < 4; ++m)
#pragma unroll
      for (int n = 0; n < 4; ++n)
        acc[m][n] = __builtin_amdgcn_mfma_f32_16x16x32_bf16(af[m], bfr[n], acc[m][n], 0, 0, 0);
  }

  const int r4 = (lane >> 4) * 4;
  const int cc = lane & 15;
#pragma unroll
  for (int m = 0; m < 4; ++m) {
    const int ib = i0 + wm * 64 + m * 16 + r4;
#pragma unroll
    for (int n = 0; n < 4; ++n) {
      const int j = j0 + wn * 64 + n * 16 + cc;
#pragma unroll
      for (int r = 0; r < 4; ++r) {
        float v = acc[m][n][r];
        if (EPI == 0) v = v * (1.0f / 513.0f);
        C[(size_t)(ib + r) * LDC + j] = v;
      }
    }
  }
}

// ---------------------------------------------------------------------------
// Kernel 3: in-place row softmax over 2048 cols + bf16 copy for PV GEMM.
// ---------------------------------------------------------------------------
__global__ __launch_bounds__(256) void softmax_kernel(
    float* __restrict__ W, __hip_bfloat16* __restrict__ Wb) {
  const size_t row = blockIdx.x;
  float* p = W + row * (size_t)Ss;
  __hip_bfloat16* pb = Wb + row * (size_t)Ss;
  const int tid = threadIdx.x;
  __shared__ float red[4];

  float v[8];
  float m = -3.0e38f;
#pragma unroll
  for (int e = 0; e < 8; ++e) { v[e] = p[tid + e * 256]; m = fmaxf(m, v[e]); }
#pragma unroll
  for (int off = 32; off > 0; off >>= 1) m = fmaxf(m, __shfl_down(m, off, 64));
  if ((tid & 63) == 0) red[tid >> 6] = m;
  __syncthreads();
  m = fmaxf(fmaxf(red[0], red[1]), fmaxf(red[2], red[3]));

  float sum = 0.0f;
#pragma unroll
  for (int e = 0; e < 8; ++e) { v[e] = expf(v[e] - m); sum += v[e]; }
#pragma unroll
  for (int off = 32; off > 0; off >>= 1) sum += __shfl_down(sum, off, 64);
  __syncthreads();
  if ((tid & 63) == 0) red[tid >> 6] = sum;
  __syncthreads();
  sum = red[0] + red[1] + red[2] + red[3];

  const float rs = 1.0f / sum;
#pragma unroll
  for (int e = 0; e < 8; ++e) {
    const float o = v[e] * rs;
    p[tid + e * 256] = o;
    pb[tid + e * 256] = __float2bfloat16(o);
  }
}

// ---------------------------------------------------------------------------
extern "C" void kernel_launch(void* const* d_in, const int* in_sizes, int n_in,
                              void* d_out, int out_size, void* d_ws, size_t ws_size,
                              hipStream_t stream) {
  const float* Q = (const float*)d_in[0];
  const float* K = (const float*)d_in[1];
  const float* V = (const float*)d_in[2];

  float* out     = (float*)d_out;                       // [B,S,H]
  float* weights = out + (size_t)Bb * Ss * Hh;          // [B,S,S]

  __hip_bfloat16* FQb = (__hip_bfloat16*)d_ws;
  __hip_bfloat16* FKb = FQb + (size_t)Bb * Ss * KP2;
  __hip_bfloat16* Vtb = FKb + (size_t)Bb * Ss * KP2;
  __hip_bfloat16* Wb  = (__hip_bfloat16*)d_ws;          // aliases dead FQb/FKb

  hipLaunchKernelGGL(fft_phase_kernel, dim3(Bb * Ss), dim3(256), 0, stream,
                     Q, K, FQb, FKb);
  hipLaunchKernelGGL(vt_kernel, dim3(Hh / 32, Ss / 32, Bb), dim3(256), 0, stream,
                     V, Vtb);
  hipLaunchKernelGGL((gemm_bt<KP2, KP2, KP2, Ss, 0>), dim3(16, 16, Bb), dim3(256), 0, stream,
                     FQb, FKb, weights,
                     (size_t)Ss * KP2, (size_t)Ss * KP2, (size_t)Ss * Ss);
  hipLaunchKernelGGL(softmax_kernel, dim3(Bb * Ss), dim3(256), 0, stream,
                     weights, Wb);
  hipLaunchKernelGGL((gemm_bt<Ss, Ss, Ss, Hh, 1>), dim3(8, 16, Bb), dim3(256), 0, stream,
                     Wb, Vtb, out,
                     (size_t)Ss * Ss, (size_t)Hh * Ss, (size_t)Ss * Hh);
}